// Round 17
// baseline (114.937 us; speedup 1.0000x reference)
//
#include <hip/hip_runtime.h>
#include <hip/hip_bf16.h>

// Per (b,c) slice: S = (Q K^T)*di ; A = softmax_rows(S) ; out[i,j] = sum_k A[j,k] V[i,k]
// ONE BLOCK PER SLICE: 1024 threads (16 waves), j-tile 256 -> K/V issued once.
// mm1: 8 chunks of 32 K-rows (Kbuf 2x16KB fp16 dbuf), 16x16x32 f16;
//      wave owns 16 j-rows; full-row softmax in registers (r13-verified).
// mm2 (r17): wave tile 64i x 64j (4 acc, operand sharing -> each A/V byte
//      LDS-read exactly ONCE per wave; 1KB LDS per 32k-FLOP MFMA).
//      V staged [256 i][64 k] fp16 (32KB, aliases Kbuf), 4 k-chunk phases,
//      2 barriers/phase; output stored once in epilogue.
// Raw s_barrier + lgkmcnt(0); LDS 160KB; 1 block/CU (16 waves = 4/SIMD).

typedef __attribute__((ext_vector_type(8))) _Float16 f16x8;
typedef __attribute__((ext_vector_type(4))) float f32x4;
typedef __attribute__((ext_vector_type(16))) float f32x16;

#define BARRIER() asm volatile("s_waitcnt lgkmcnt(0)\n\ts_barrier" ::: "memory")

__device__ __forceinline__ f32x4 mfma16h(f16x8 a, f16x8 b, f32x4 c) {
  return __builtin_amdgcn_mfma_f32_16x16x32_f16(a, b, c, 0, 0, 0);
}
__device__ __forceinline__ f32x16 mfma32h(f16x8 a, f16x8 b, f32x16 c) {
  return __builtin_amdgcn_mfma_f32_32x32x16_f16(a, b, c, 0, 0, 0);
}
__device__ __forceinline__ f16x8 cvt8(f32x4 a, f32x4 b) {
  f16x8 r;
  r[0] = (_Float16)a[0]; r[1] = (_Float16)a[1];
  r[2] = (_Float16)a[2]; r[3] = (_Float16)a[3];
  r[4] = (_Float16)b[0]; r[5] = (_Float16)b[1];
  r[6] = (_Float16)b[2]; r[7] = (_Float16)b[3];
  return r;
}
// 512B-row-stride fp16 tiles ([*][256]): XOR 4 row bits into the 16B-slot idx
__device__ __forceinline__ int swzA(int row, int byteCol) {
  return row * 512 + (byteCol ^ ((row & 15) << 4));
}
// 128B-row-stride fp16 tile ([256 i][64 k]): 3-bit XOR (r3-verified layout)
__device__ __forceinline__ int swzV(int row, int byteCol) {
  return row * 128 + (byteCol ^ ((row & 7) << 4));
}

__global__ __launch_bounds__(1024, 4) void attn_fused17(
    const float* __restrict__ Q, const float* __restrict__ K,
    const float* __restrict__ V, const float* __restrict__ di,
    float* __restrict__ out) {
  __shared__ short Kbuf[2][32 * 256];  // 2 x 16KB fp16 K chunks (mm1)
  __shared__ short Abuf[256 * 256];    // 128KB fp16 attn weights, swizzled
  short* Vlds = &Kbuf[0][0];           // mm2: [256 i][64 k] fp16 = 32KB alias

  const int t = threadIdx.x;
  const int lane = t & 63;
  const int wv = t >> 6;     // 0..15
  const int l15 = lane & 15;
  const int l4 = (lane >> 4) & 3;
  const int l31 = lane & 31;
  const int h5 = lane >> 5;

  const int bc = blockIdx.x;  // slice 0..511 (block owns whole slice)

  const float dival = di[0];
  const size_t base = (size_t)bc << 16;
  const float* Qs = Q + base;
  const float* Ks = K + base;
  const float* Vs = V + base;
  float* Os = out + base;

  // K staging: thread loads 8 consecutive floats of a 32x256 chunk,
  // writes one swizzled 16B fp16 slot.
  const int sr = t >> 5;          // row 0..31
  const int scf = (t & 31) << 3;  // float col (8 per thread)

  f32x4 kpA0, kpA1, kpB0, kpB1;  // 2-deep K prefetch (chunks ch, ch+1)
  {
    const float* p = Ks + sr * 256 + scf;
    kpA0 = *(const f32x4*)p;
    kpA1 = *(const f32x4*)(p + 4);
    kpB0 = *(const f32x4*)(p + 8192);
    kpB1 = *(const f32x4*)(p + 8192 + 4);
  }
  f16x8 qh[8];  // wave's 16 Q rows (A-op layout)
  {
    const float* qrow = Qs + (size_t)(16 * wv + l15) * 256 + 8 * l4;
#pragma unroll
    for (int s = 0; s < 8; ++s)
      qh[s] = cvt8(*(const f32x4*)(qrow + 32 * s),
                   *(const f32x4*)(qrow + 32 * s + 4));
  }

  f32x4 acc[16];  // S rows j=16wv+4l4+r ; cols k = 16*idx + l15
#pragma unroll
  for (int i = 0; i < 16; ++i) acc[i] = (f32x4){0.f, 0.f, 0.f, 0.f};

  // ---- matmul 1: 8 chunks of 32 k-rows, single barrier per chunk ----
#pragma unroll
  for (int ch = 0; ch < 8; ++ch) {
    short* kb = Kbuf[ch & 1];
    if ((ch & 1) == 0) {
      *(f16x8*)((char*)kb + swzA(sr, scf * 2)) = cvt8(kpA0, kpA1);
    } else {
      *(f16x8*)((char*)kb + swzA(sr, scf * 2)) = cvt8(kpB0, kpB1);
    }
    BARRIER();
    if (ch < 6) {  // prefetch chunk ch+2 into the freed parity regs
      const float* p = Ks + (ch + 2) * 8192 + sr * 256 + scf;
      if ((ch & 1) == 0) {
        kpA0 = *(const f32x4*)p;
        kpA1 = *(const f32x4*)(p + 4);
      } else {
        kpB0 = *(const f32x4*)p;
        kpB1 = *(const f32x4*)(p + 4);
      }
    }
    __builtin_amdgcn_s_setprio(1);
#pragma unroll
    for (int kf = 0; kf < 2; ++kf) {
      const int kr = 16 * kf + l15;
      f32x4 a = acc[2 * ch + kf];
#pragma unroll
      for (int s = 0; s < 8; ++s) {
        f16x8 bh =
            *(const f16x8*)((const char*)kb + swzA(kr, 64 * s + 16 * l4));
        a = mfma16h(qh[s], bh, a);
      }
      acc[2 * ch + kf] = a;
    }
    __builtin_amdgcn_s_setprio(0);
  }

  // ---- V prefetch for mm2 phase 0 (flies under softmax) ----
  // thread loads 16 floats of the [256 i][64 k] chunk: row t>>2, cols 16*(t&3)
  const int vr = t >> 2;          // V-tile row 0..255
  const int vq = (t & 3) << 4;    // float col within 64-col chunk
  f32x4 vp[4];
  {
    const float* p = Vs + (size_t)vr * 256 + vq;  // kc=0
#pragma unroll
    for (int e = 0; e < 4; ++e) vp[e] = *(const f32x4*)(p + 4 * e);
  }

  // ---- softmax: full k per wave, in-register (r13-verified) ----
  float mx[4] = {-1e30f, -1e30f, -1e30f, -1e30f};
#pragma unroll
  for (int idx = 0; idx < 16; ++idx)
#pragma unroll
    for (int r = 0; r < 4; ++r) {
      acc[idx][r] *= dival;
      mx[r] = fmaxf(mx[r], acc[idx][r]);
    }
#pragma unroll
  for (int o = 1; o <= 8; o <<= 1)
#pragma unroll
    for (int r = 0; r < 4; ++r) mx[r] = fmaxf(mx[r], __shfl_xor(mx[r], o));
  float sm[4] = {0.f, 0.f, 0.f, 0.f};
#pragma unroll
  for (int idx = 0; idx < 16; ++idx)
#pragma unroll
    for (int r = 0; r < 4; ++r) {
      acc[idx][r] = __expf(acc[idx][r] - mx[r]);
      sm[r] += acc[idx][r];
    }
#pragma unroll
  for (int o = 1; o <= 8; o <<= 1)
#pragma unroll
    for (int r = 0; r < 4; ++r) sm[r] += __shfl_xor(sm[r], o);
#pragma unroll
  for (int r = 0; r < 4; ++r) sm[r] = 1.0f / sm[r];
#pragma unroll
  for (int idx = 0; idx < 16; ++idx)
#pragma unroll
    for (int r = 0; r < 4; ++r) {
      const int row = 16 * wv + 4 * l4 + r;
      *(_Float16*)((char*)Abuf + swzA(row, 2 * (16 * idx + l15))) =
          (_Float16)(acc[idx][r] * sm[r]);
    }
  BARRIER();  // A visible; all mm1 Kbuf reads done (Vlds alias safe)

  // ---- matmul 2: 4 k-chunk phases; wave tile 64i x 64j ----
  const int ig = wv & 3;   // i 64-group
  const int jg = wv >> 2;  // j 64-group
  f32x16 o00 = {}, o01 = {}, o10 = {}, o11 = {};
#pragma unroll
  for (int kc = 0; kc < 4; ++kc) {
    // stage V chunk [256][64] from prefetch regs (2 x 16B swizzled writes)
    *(f16x8*)((char*)Vlds + swzV(vr, 2 * vq)) = cvt8(vp[0], vp[1]);
    *(f16x8*)((char*)Vlds + swzV(vr, 2 * vq + 16)) = cvt8(vp[2], vp[3]);
    BARRIER();  // stage visible
    if (kc < 3) {  // issue next chunk's loads; fly under this phase's MFMA
      const float* p = Vs + (size_t)vr * 256 + (kc + 1) * 64 + vq;
#pragma unroll
      for (int e = 0; e < 4; ++e) vp[e] = *(const f32x4*)(p + 4 * e);
    }
    __builtin_amdgcn_s_setprio(1);
#pragma unroll
    for (int kk = 0; kk < 4; ++kk) {
      const int vCol = 32 * kk + 16 * h5;
      f16x8 va0 =
          *(const f16x8*)((const char*)Vlds + swzV(64 * ig + l31, vCol));
      f16x8 va1 =
          *(const f16x8*)((const char*)Vlds + swzV(64 * ig + 32 + l31, vCol));
      const int aCol = 128 * kc + 32 * kk + 16 * h5;
      f16x8 pb0 =
          *(const f16x8*)((const char*)Abuf + swzA(64 * jg + l31, aCol));
      f16x8 pb1 =
          *(const f16x8*)((const char*)Abuf + swzA(64 * jg + 32 + l31, aCol));
      o00 = mfma32h(va0, pb0, o00);
      o01 = mfma32h(va0, pb1, o01);
      o10 = mfma32h(va1, pb0, o10);
      o11 = mfma32h(va1, pb1, o11);
    }
    __builtin_amdgcn_s_setprio(0);
    if (kc < 3) BARRIER();  // reads done before next stage overwrite
  }

  // ---- epilogue: store the wave's 64x64 block ----
  const int rb = 64 * ig + 4 * h5;
  const int cb = 64 * jg + l31;
#pragma unroll
  for (int reg = 0; reg < 16; ++reg) {
    const int rw = (reg & 3) + 8 * (reg >> 2);
    Os[(size_t)(rb + rw) * 256 + cb] = o00[reg];
    Os[(size_t)(rb + rw) * 256 + cb + 32] = o01[reg];
    Os[(size_t)(rb + 32 + rw) * 256 + cb] = o10[reg];
    Os[(size_t)(rb + 32 + rw) * 256 + cb + 32] = o11[reg];
  }
}

extern "C" void kernel_launch(void* const* d_in, const int* in_sizes, int n_in,
                              void* d_out, int out_size, void* d_ws,
                              size_t ws_size, hipStream_t stream) {
  const float* Q = (const float*)d_in[0];
  const float* K = (const float*)d_in[1];
  const float* V = (const float*)d_in[2];
  const float* di = (const float*)d_in[3];
  float* out = (float*)d_out;
  const int BC = in_sizes[0] / (256 * 256);  // 512 slices
  hipLaunchKernelGGL(attn_fused17, dim3(BC), dim3(1024), 0, stream, Q, K, V,
                     di, out);
}

// Round 18
// 106.632 us; speedup vs baseline: 1.0779x; 1.0779x over previous
//
#include <hip/hip_runtime.h>
#include <hip/hip_bf16.h>

// Per (b,c) slice: S = (Q K^T)*di ; A = softmax_rows(S) ; out[i,j] = sum_k A[j,k] V[i,k]
// ONE BLOCK PER SLICE: 1024 threads (16 waves), j-tile 256 -> K/V issued once.
// mm1: 8 chunks of 32 K-rows (Kbuf 2x16KB fp16 dbuf), 16x16x32 f16;
//      wave owns 16 j-rows; full-row softmax in registers (r13-verified).
// mm2: 8 phases = 4 i-chunks x 2 k-halves, V [64i][128k] fp16 double-buffered.
// r18: A k-half-0 panel preloaded to registers (pb0[8] = 32 VGPR, fits the
//      ~48 unified regs free after mm1's acc/qh/kp die) -> kh=0 phases do
//      zero A-LDS reads. Everything else r13-identical.
// Raw s_barrier + lgkmcnt(0); LDS 160KB; 1 block/CU (16 waves = 4/SIMD).

typedef __attribute__((ext_vector_type(8))) _Float16 f16x8;
typedef __attribute__((ext_vector_type(4))) float f32x4;
typedef __attribute__((ext_vector_type(16))) float f32x16;

#define BARRIER() asm volatile("s_waitcnt lgkmcnt(0)\n\ts_barrier" ::: "memory")

__device__ __forceinline__ f32x4 mfma16h(f16x8 a, f16x8 b, f32x4 c) {
  return __builtin_amdgcn_mfma_f32_16x16x32_f16(a, b, c, 0, 0, 0);
}
__device__ __forceinline__ f32x16 mfma32h(f16x8 a, f16x8 b, f32x16 c) {
  return __builtin_amdgcn_mfma_f32_32x32x16_f16(a, b, c, 0, 0, 0);
}
__device__ __forceinline__ f16x8 cvt8(f32x4 a, f32x4 b) {
  f16x8 r;
  r[0] = (_Float16)a[0]; r[1] = (_Float16)a[1];
  r[2] = (_Float16)a[2]; r[3] = (_Float16)a[3];
  r[4] = (_Float16)b[0]; r[5] = (_Float16)b[1];
  r[6] = (_Float16)b[2]; r[7] = (_Float16)b[3];
  return r;
}
// 512B-row-stride fp16 tiles ([*][256]): XOR 4 row bits into the 16B-slot idx
__device__ __forceinline__ int swzA(int row, int byteCol) {
  return row * 512 + (byteCol ^ ((row & 15) << 4));
}
// 256B-row-stride fp16 tile ([64][128]): 4-bit XOR over 16 slots
__device__ __forceinline__ int swzV(int row, int byteCol) {
  return row * 256 + (byteCol ^ ((row & 15) << 4));
}

__global__ __launch_bounds__(1024, 4) void attn_fused18(
    const float* __restrict__ Q, const float* __restrict__ K,
    const float* __restrict__ V, const float* __restrict__ di,
    float* __restrict__ out) {
  __shared__ short Kbuf[2][32 * 256];  // 2 x 16KB fp16 K chunks; alias: Vlds
  __shared__ short Abuf[256 * 256];    // 128KB fp16 attn weights, swizzled
  short* Vlds0 = &Kbuf[0][0];          // mm2 V dbuf half 0 (16KB)
  short* Vlds1 = &Kbuf[1][0];          // mm2 V dbuf half 1 (16KB)

  const int t = threadIdx.x;
  const int lane = t & 63;
  const int wv = t >> 6;     // 0..15
  const int l15 = lane & 15;
  const int l4 = (lane >> 4) & 3;
  const int l31 = lane & 31;
  const int h5 = lane >> 5;

  const int bc = blockIdx.x;  // slice 0..511 (block owns whole slice)

  const float dival = di[0];
  const size_t base = (size_t)bc << 16;
  const float* Qs = Q + base;
  const float* Ks = K + base;
  const float* Vs = V + base;
  float* Os = out + base;

  // K staging: thread loads 8 consecutive floats of a 32x256 chunk,
  // writes one swizzled 16B fp16 slot.
  const int sr = t >> 5;          // row 0..31
  const int scf = (t & 31) << 3;  // float col (8 per thread)

  f32x4 kpA0, kpA1, kpB0, kpB1;  // 2-deep K prefetch (chunks ch, ch+1)
  {
    const float* p = Ks + sr * 256 + scf;
    kpA0 = *(const f32x4*)p;
    kpA1 = *(const f32x4*)(p + 4);
    kpB0 = *(const f32x4*)(p + 8192);
    kpB1 = *(const f32x4*)(p + 8192 + 4);
  }
  f16x8 qh[8];  // wave's 16 Q rows (A-op layout)
  {
    const float* qrow = Qs + (size_t)(16 * wv + l15) * 256 + 8 * l4;
#pragma unroll
    for (int s = 0; s < 8; ++s)
      qh[s] = cvt8(*(const f32x4*)(qrow + 32 * s),
                   *(const f32x4*)(qrow + 32 * s + 4));
  }

  f32x4 acc[16];  // S rows j=16wv+4l4+r ; cols k = 16*idx + l15
#pragma unroll
  for (int i = 0; i < 16; ++i) acc[i] = (f32x4){0.f, 0.f, 0.f, 0.f};

  // ---- matmul 1: 8 chunks of 32 k-rows, single barrier per chunk ----
#pragma unroll
  for (int ch = 0; ch < 8; ++ch) {
    short* kb = Kbuf[ch & 1];
    if ((ch & 1) == 0) {
      *(f16x8*)((char*)kb + swzA(sr, scf * 2)) = cvt8(kpA0, kpA1);
    } else {
      *(f16x8*)((char*)kb + swzA(sr, scf * 2)) = cvt8(kpB0, kpB1);
    }
    BARRIER();
    if (ch < 6) {  // prefetch chunk ch+2 into the freed parity regs
      const float* p = Ks + (ch + 2) * 8192 + sr * 256 + scf;
      if ((ch & 1) == 0) {
        kpA0 = *(const f32x4*)p;
        kpA1 = *(const f32x4*)(p + 4);
      } else {
        kpB0 = *(const f32x4*)p;
        kpB1 = *(const f32x4*)(p + 4);
      }
    }
    __builtin_amdgcn_s_setprio(1);
#pragma unroll
    for (int kf = 0; kf < 2; ++kf) {
      const int kr = 16 * kf + l15;
      f32x4 a = acc[2 * ch + kf];
#pragma unroll
      for (int s = 0; s < 8; ++s) {
        f16x8 bh =
            *(const f16x8*)((const char*)kb + swzA(kr, 64 * s + 16 * l4));
        a = mfma16h(qh[s], bh, a);
      }
      acc[2 * ch + kf] = a;
    }
    __builtin_amdgcn_s_setprio(0);
  }

  // ---- V prefetch for mm2 phases 0,1 (fly under softmax) ----
  const int vr = t >> 4;         // V-tile row 0..63
  const int vcf = (t & 15) * 8;  // float col within 128-col half
  f32x4 vpA[2], vpB[2];
  {
    const float* p = Vs + (size_t)vr * 256 + vcf;  // ic=0, kh=0
    vpA[0] = *(const f32x4*)p;
    vpA[1] = *(const f32x4*)(p + 4);
    const float* q = p + 128;  // ic=0, kh=1
    vpB[0] = *(const f32x4*)q;
    vpB[1] = *(const f32x4*)(q + 4);
  }

  // ---- softmax: full k per wave, in-register (r13-verified) ----
  float mx[4] = {-1e30f, -1e30f, -1e30f, -1e30f};
#pragma unroll
  for (int idx = 0; idx < 16; ++idx)
#pragma unroll
    for (int r = 0; r < 4; ++r) {
      acc[idx][r] *= dival;
      mx[r] = fmaxf(mx[r], acc[idx][r]);
    }
#pragma unroll
  for (int o = 1; o <= 8; o <<= 1)
#pragma unroll
    for (int r = 0; r < 4; ++r) mx[r] = fmaxf(mx[r], __shfl_xor(mx[r], o));
  float sm[4] = {0.f, 0.f, 0.f, 0.f};
#pragma unroll
  for (int idx = 0; idx < 16; ++idx)
#pragma unroll
    for (int r = 0; r < 4; ++r) {
      acc[idx][r] = __expf(acc[idx][r] - mx[r]);
      sm[r] += acc[idx][r];
    }
#pragma unroll
  for (int o = 1; o <= 8; o <<= 1)
#pragma unroll
    for (int r = 0; r < 4; ++r) sm[r] += __shfl_xor(sm[r], o);
#pragma unroll
  for (int r = 0; r < 4; ++r) sm[r] = 1.0f / sm[r];
#pragma unroll
  for (int idx = 0; idx < 16; ++idx)
#pragma unroll
    for (int r = 0; r < 4; ++r) {
      const int row = 16 * wv + 4 * l4 + r;
      *(_Float16*)((char*)Abuf + swzA(row, 2 * (16 * idx + l15))) =
          (_Float16)(acc[idx][r] * sm[r]);
    }
  BARRIER();  // A visible; all mm1 Kbuf reads done (Vlds alias safe)

  // ---- preload A k-half-0 panel (32 VGPR; acc/qh/kp now dead) ----
  const int ig = wv & 1;   // i 32-group within 64-row chunk
  const int jg = wv >> 1;  // j 32-group (0..7)
  f16x8 pb0[8];            // pb0[kk] = A[32jg+l31][32kk + 16h5 ..], kh=0
#pragma unroll
  for (int kk = 0; kk < 8; ++kk)
    pb0[kk] = *(const f16x8*)((const char*)Abuf +
                              swzA(32 * jg + l31, 32 * kk + 16 * h5));

  // ---- matmul 2: 8 phases = 4 i-chunks(64) x 2 k-halves(128), V dbuf ----
  f32x16 o = {};
#pragma unroll
  for (int cc = 0; cc < 8; ++cc) {
    const int kh = cc & 1;
    short* vb = (cc & 1) ? Vlds1 : Vlds0;  // dbuf by parity
    if ((cc & 1) == 0) {
      *(f16x8*)((char*)vb + swzV(vr, 2 * vcf)) = cvt8(vpA[0], vpA[1]);
    } else {
      *(f16x8*)((char*)vb + swzV(vr, 2 * vcf)) = cvt8(vpB[0], vpB[1]);
    }
    BARRIER();  // single barrier per phase (dbuf)
    if (cc < 6) {  // prefetch phase cc+2 into freed parity regs
      const float* p = Vs + (size_t)(64 * ((cc + 2) >> 1) + vr) * 256 +
                       ((cc & 1) ? 128 : 0) + vcf;
      if ((cc & 1) == 0) {
        vpA[0] = *(const f32x4*)p;
        vpA[1] = *(const f32x4*)(p + 4);
      } else {
        vpB[0] = *(const f32x4*)p;
        vpB[1] = *(const f32x4*)(p + 4);
      }
    }
    __builtin_amdgcn_s_setprio(1);
    if (kh == 0) {
#pragma unroll
      for (int kk = 0; kk < 8; ++kk) {
        f16x8 vfrag = *(const f16x8*)((const char*)vb +
                                      swzV(32 * ig + l31, 32 * kk + 16 * h5));
        o = mfma32h(vfrag, pb0[kk], o);  // zero A-LDS reads this phase
      }
    } else {
#pragma unroll
      for (int kk = 0; kk < 8; ++kk) {
        f16x8 vfrag = *(const f16x8*)((const char*)vb +
                                      swzV(32 * ig + l31, 32 * kk + 16 * h5));
        f16x8 pfrag =
            *(const f16x8*)((const char*)Abuf +
                            swzA(32 * jg + l31, 256 + 32 * kk + 16 * h5));
        o = mfma32h(vfrag, pfrag, o);
      }
    }
    __builtin_amdgcn_s_setprio(0);
    if (kh == 1) {  // both k-halves accumulated: store this i-chunk
      const int rbase = 64 * (cc >> 1) + 32 * ig + 4 * h5;
      const int col = 32 * jg + l31;
#pragma unroll
      for (int reg = 0; reg < 16; ++reg) {
        const int rw = (reg & 3) + 8 * (reg >> 2);
        Os[(size_t)(rbase + rw) * 256 + col] = o[reg];
      }
      o = (f32x16){};
    }
  }
}

extern "C" void kernel_launch(void* const* d_in, const int* in_sizes, int n_in,
                              void* d_out, int out_size, void* d_ws,
                              size_t ws_size, hipStream_t stream) {
  const float* Q = (const float*)d_in[0];
  const float* K = (const float*)d_in[1];
  const float* V = (const float*)d_in[2];
  const float* di = (const float*)d_in[3];
  float* out = (float*)d_out;
  const int BC = in_sizes[0] / (256 * 256);  // 512 slices
  hipLaunchKernelGGL(attn_fused18, dim3(BC), dim3(1024), 0, stream, Q, K, V,
                     di, out);
}

// Round 19
// 105.221 us; speedup vs baseline: 1.0923x; 1.0134x over previous
//
#include <hip/hip_runtime.h>
#include <hip/hip_bf16.h>

// Per (b,c) slice: S = (Q K^T)*di ; A = softmax_rows(S) ; out[i,j] = sum_k A[j,k] V[i,k]
// ONE BLOCK PER SLICE: 1024 threads (16 waves), j-tile 256 -> K/V issued once.
// mm1 (r19): S^T via mfma(K,Q) -> lane holds 4 CONSECUTIVE k per j ->
//      A-write is 16 packed ds_write_b64 (was 64 scalar b16); softmax row is
//      lane-local: in-lane reduce + 2 shfl levels. Same A layout -> mm2 as r13.
// mm2: 8 phases = 4 i-chunks x 2 k-halves, V [64i][128k] fp16 double-buffered.
// Raw s_barrier + lgkmcnt(0); LDS 160KB; 1 block/CU (16 waves = 4/SIMD).

typedef __attribute__((ext_vector_type(8))) _Float16 f16x8;
typedef __attribute__((ext_vector_type(2))) __fp16 fp16v2;
typedef __attribute__((ext_vector_type(4))) float f32x4;
typedef __attribute__((ext_vector_type(16))) float f32x16;
typedef __attribute__((ext_vector_type(2))) unsigned u32x2;

#define BARRIER() asm volatile("s_waitcnt lgkmcnt(0)\n\ts_barrier" ::: "memory")

__device__ __forceinline__ f32x4 mfma16h(f16x8 a, f16x8 b, f32x4 c) {
  return __builtin_amdgcn_mfma_f32_16x16x32_f16(a, b, c, 0, 0, 0);
}
__device__ __forceinline__ f32x16 mfma32h(f16x8 a, f16x8 b, f32x16 c) {
  return __builtin_amdgcn_mfma_f32_32x32x16_f16(a, b, c, 0, 0, 0);
}
__device__ __forceinline__ f16x8 cvt8(f32x4 a, f32x4 b) {
  f16x8 r;
  r[0] = (_Float16)a[0]; r[1] = (_Float16)a[1];
  r[2] = (_Float16)a[2]; r[3] = (_Float16)a[3];
  r[4] = (_Float16)b[0]; r[5] = (_Float16)b[1];
  r[6] = (_Float16)b[2]; r[7] = (_Float16)b[3];
  return r;
}
__device__ __forceinline__ f16x8 cvt8s(f32x4 a, f32x4 b, float s) {
  f16x8 r;
  r[0] = (_Float16)(a[0] * s); r[1] = (_Float16)(a[1] * s);
  r[2] = (_Float16)(a[2] * s); r[3] = (_Float16)(a[3] * s);
  r[4] = (_Float16)(b[0] * s); r[5] = (_Float16)(b[1] * s);
  r[6] = (_Float16)(b[2] * s); r[7] = (_Float16)(b[3] * s);
  return r;
}
__device__ __forceinline__ unsigned pk2(float a, float b) {
  fp16v2 h = __builtin_amdgcn_cvt_pkrtz(a, b);
  return __builtin_bit_cast(unsigned, h);
}
// 512B-row-stride fp16 tiles ([*][256]): XOR 4 row bits into the 16B-slot idx
__device__ __forceinline__ int swzA(int row, int byteCol) {
  return row * 512 + (byteCol ^ ((row & 15) << 4));
}
// 256B-row-stride fp16 tile ([64][128]): 4-bit XOR over 16 slots
__device__ __forceinline__ int swzV(int row, int byteCol) {
  return row * 256 + (byteCol ^ ((row & 15) << 4));
}

__global__ __launch_bounds__(1024, 4) void attn_fused19(
    const float* __restrict__ Q, const float* __restrict__ K,
    const float* __restrict__ V, const float* __restrict__ di,
    float* __restrict__ out) {
  __shared__ short Kbuf[2][32 * 256];  // 2 x 16KB fp16 K chunks; alias: Vlds
  __shared__ short Abuf[256 * 256];    // 128KB fp16 attn weights, swizzled
  short* Vlds0 = &Kbuf[0][0];          // mm2 V dbuf half 0 (16KB)
  short* Vlds1 = &Kbuf[1][0];          // mm2 V dbuf half 1 (16KB)

  const int t = threadIdx.x;
  const int lane = t & 63;
  const int wv = t >> 6;     // 0..15
  const int l15 = lane & 15;
  const int l4 = (lane >> 4) & 3;
  const int l31 = lane & 31;
  const int h5 = lane >> 5;

  const int bc = blockIdx.x;  // slice 0..511 (block owns whole slice)

  const float dival = di[0];
  const size_t base = (size_t)bc << 16;
  const float* Qs = Q + base;
  const float* Ks = K + base;
  const float* Vs = V + base;
  float* Os = out + base;

  // K staging: thread loads 8 consecutive floats of a 32x256 chunk,
  // writes one swizzled 16B fp16 slot.
  const int sr = t >> 5;          // row 0..31
  const int scf = (t & 31) << 3;  // float col (8 per thread)

  f32x4 kpA0, kpA1, kpB0, kpB1;  // 2-deep K prefetch (chunks ch, ch+1)
  {
    const float* p = Ks + sr * 256 + scf;
    kpA0 = *(const f32x4*)p;
    kpA1 = *(const f32x4*)(p + 4);
    kpB0 = *(const f32x4*)(p + 8192);
    kpB1 = *(const f32x4*)(p + 8192 + 4);
  }
  // Q fragments, di pre-folded. B-operand role: lane l15 = j-col, w = 32s+8l4+e
  // (same bytes as the r13 A-operand load — layouts coincide).
  f16x8 qh[8];
  {
    const float* qrow = Qs + (size_t)(16 * wv + l15) * 256 + 8 * l4;
#pragma unroll
    for (int s = 0; s < 8; ++s)
      qh[s] = cvt8s(*(const f32x4*)(qrow + 32 * s),
                    *(const f32x4*)(qrow + 32 * s + 4), dival);
  }

  // acc = S^T fragments: j = 16wv + l15 (per lane), k = 16*idx + 4*l4 + r
  f32x4 acc[16];
#pragma unroll
  for (int i = 0; i < 16; ++i) acc[i] = (f32x4){0.f, 0.f, 0.f, 0.f};

  // ---- matmul 1: 8 chunks of 32 k-rows, single barrier per chunk ----
#pragma unroll
  for (int ch = 0; ch < 8; ++ch) {
    short* kb = Kbuf[ch & 1];
    if ((ch & 1) == 0) {
      *(f16x8*)((char*)kb + swzA(sr, scf * 2)) = cvt8(kpA0, kpA1);
    } else {
      *(f16x8*)((char*)kb + swzA(sr, scf * 2)) = cvt8(kpB0, kpB1);
    }
    BARRIER();
    if (ch < 6) {  // prefetch chunk ch+2 into the freed parity regs
      const float* p = Ks + (ch + 2) * 8192 + sr * 256 + scf;
      if ((ch & 1) == 0) {
        kpA0 = *(const f32x4*)p;
        kpA1 = *(const f32x4*)(p + 4);
      } else {
        kpB0 = *(const f32x4*)p;
        kpB1 = *(const f32x4*)(p + 4);
      }
    }
    __builtin_amdgcn_s_setprio(1);
#pragma unroll
    for (int kf = 0; kf < 2; ++kf) {
      const int kr = 16 * kf + l15;  // K-row (A-operand row = l15)
      f32x4 a = acc[2 * ch + kf];
#pragma unroll
      for (int s = 0; s < 8; ++s) {
        f16x8 bh =
            *(const f16x8*)((const char*)kb + swzA(kr, 64 * s + 16 * l4));
        a = mfma16h(bh, qh[s], a);  // swapped: D = S^T (row=k-local, col=j)
      }
      acc[2 * ch + kf] = a;
    }
    __builtin_amdgcn_s_setprio(0);
  }

  // ---- V prefetch for mm2 phases 0,1 (fly under softmax) ----
  const int vr = t >> 4;         // V-tile row 0..63
  const int vcf = (t & 15) * 8;  // float col within 128-col half
  f32x4 vpA[2], vpB[2];
  {
    const float* p = Vs + (size_t)vr * 256 + vcf;  // ic=0, kh=0
    vpA[0] = *(const f32x4*)p;
    vpA[1] = *(const f32x4*)(p + 4);
    const float* q = p + 128;  // ic=0, kh=1
    vpB[0] = *(const f32x4*)q;
    vpB[1] = *(const f32x4*)(q + 4);
  }

  // ---- softmax: row j = 16wv+l15 is lane-local; combine over l4 via 2 shfl ----
  float mrow = -1e30f;
#pragma unroll
  for (int idx = 0; idx < 16; ++idx)
#pragma unroll
    for (int r = 0; r < 4; ++r) mrow = fmaxf(mrow, acc[idx][r]);
  mrow = fmaxf(mrow, __shfl_xor(mrow, 16));
  mrow = fmaxf(mrow, __shfl_xor(mrow, 32));
  float srow = 0.f;
#pragma unroll
  for (int idx = 0; idx < 16; ++idx)
#pragma unroll
    for (int r = 0; r < 4; ++r) {
      acc[idx][r] = __expf(acc[idx][r] - mrow);
      srow += acc[idx][r];
    }
  srow += __shfl_xor(srow, 16);
  srow += __shfl_xor(srow, 32);
  const float inv = 1.0f / srow;
  // packed A-write: row j, k = 16*idx + 4*l4 + {0..3} -> one b64 per idx
  {
    const int row = 16 * wv + l15;
    char* abase = (char*)Abuf + row * 512;
    const int xr = (l15 << 4);  // (row & 15) << 4
#pragma unroll
    for (int idx = 0; idx < 16; ++idx) {
      u32x2 w;
      w[0] = pk2(acc[idx][0] * inv, acc[idx][1] * inv);
      w[1] = pk2(acc[idx][2] * inv, acc[idx][3] * inv);
      *(u32x2*)(abase + ((32 * idx + 8 * l4) ^ xr)) = w;
    }
  }
  BARRIER();  // A visible; all mm1 Kbuf reads done (Vlds alias safe)

  // ---- matmul 2: 8 phases = 4 i-chunks(64) x 2 k-halves(128), V dbuf ----
  const int ig = wv & 1;   // i 32-group within 64-row chunk
  const int jg = wv >> 1;  // j 32-group (0..7)
  f32x16 o = {};
#pragma unroll
  for (int cc = 0; cc < 8; ++cc) {
    const int kh = cc & 1;
    short* vb = (cc & 1) ? Vlds1 : Vlds0;  // dbuf by parity
    if ((cc & 1) == 0) {
      *(f16x8*)((char*)vb + swzV(vr, 2 * vcf)) = cvt8(vpA[0], vpA[1]);
    } else {
      *(f16x8*)((char*)vb + swzV(vr, 2 * vcf)) = cvt8(vpB[0], vpB[1]);
    }
    BARRIER();  // single barrier per phase (dbuf)
    if (cc < 6) {  // prefetch phase cc+2 into freed parity regs
      const float* p = Vs + (size_t)(64 * ((cc + 2) >> 1) + vr) * 256 +
                       ((cc & 1) ? 128 : 0) + vcf;
      if ((cc & 1) == 0) {
        vpA[0] = *(const f32x4*)p;
        vpA[1] = *(const f32x4*)(p + 4);
      } else {
        vpB[0] = *(const f32x4*)p;
        vpB[1] = *(const f32x4*)(p + 4);
      }
    }
    __builtin_amdgcn_s_setprio(1);
#pragma unroll
    for (int kk = 0; kk < 8; ++kk) {
      f16x8 vfrag = *(const f16x8*)((const char*)vb +
                                    swzV(32 * ig + l31, 32 * kk + 16 * h5));
      f16x8 pfrag =
          *(const f16x8*)((const char*)Abuf +
                          swzA(32 * jg + l31, 256 * kh + 32 * kk + 16 * h5));
      o = mfma32h(vfrag, pfrag, o);
    }
    __builtin_amdgcn_s_setprio(0);
    if (kh == 1) {  // both k-halves accumulated: store this i-chunk
      const int rbase = 64 * (cc >> 1) + 32 * ig + 4 * h5;
      const int col = 32 * jg + l31;
#pragma unroll
      for (int reg = 0; reg < 16; ++reg) {
        const int rw = (reg & 3) + 8 * (reg >> 2);
        Os[(size_t)(rbase + rw) * 256 + col] = o[reg];
      }
      o = (f32x16){};
    }
  }
}

extern "C" void kernel_launch(void* const* d_in, const int* in_sizes, int n_in,
                              void* d_out, int out_size, void* d_ws,
                              size_t ws_size, hipStream_t stream) {
  const float* Q = (const float*)d_in[0];
  const float* K = (const float*)d_in[1];
  const float* V = (const float*)d_in[2];
  const float* di = (const float*)d_in[3];
  float* out = (float*)d_out;
  const int BC = in_sizes[0] / (256 * 256);  // 512 slices
  hipLaunchKernelGGL(attn_fused19, dim3(BC), dim3(1024), 0, stream, Q, K, V,
                     di, out);
}